// Round 1
// baseline (221.599 us; speedup 1.0000x reference)
//
#include <hip/hip_runtime.h>
#include <hip/hip_bf16.h>
#include <stdint.h>

#define NPTS 81920
#define CIN  64
#define COUT 128
#define BATCH 4
#define KNB  10
#define CK   640      // CIN*KNB
#define NSTEP 20      // CK/32

typedef __attribute__((ext_vector_type(8))) short bf16x8;
typedef __attribute__((ext_vector_type(4))) float f32x4;

static __device__ __forceinline__ unsigned short f2bf(float f) {
    unsigned int u = __float_as_uint(f);
    u += 0x7fffu + ((u >> 16) & 1u);      // RNE, finite inputs
    return (unsigned short)(u >> 16);
}

// ---------------------------------------------------------------------------
// Kernel 1: x (B, CIN, N) f32  ->  xT (B, N, CIN) bf16  (gather rows contiguous)
// ---------------------------------------------------------------------------
__global__ __launch_bounds__(256) void k_transpose(const float* __restrict__ x,
                                                   unsigned short* __restrict__ xT) {
    const int m = blockIdx.x * 256 + threadIdx.x;
    const int b = blockIdx.y;
    const float* xb = x + (size_t)b * CIN * NPTS + m;

    unsigned int v[CIN / 2];
    #pragma unroll
    for (int i = 0; i < CIN / 2; ++i) {
        float f0 = xb[(size_t)(2 * i) * NPTS];       // coalesced across lanes
        float f1 = xb[(size_t)(2 * i + 1) * NPTS];
        v[i] = (unsigned int)f2bf(f0) | ((unsigned int)f2bf(f1) << 16);
    }
    uint4* dst = (uint4*)(xT + ((size_t)b * NPTS + m) * CIN);
    #pragma unroll
    for (int i = 0; i < 8; ++i) {
        uint4 w; w.x = v[4*i]; w.y = v[4*i+1]; w.z = v[4*i+2]; w.w = v[4*i+3];
        dst[i] = w;                                   // 128 B contiguous per lane
    }
}

// ---------------------------------------------------------------------------
// Kernel 2: W (COUT, CIN, KNB) f32 -> Wb bf16 in MFMA-fragment order:
//   element index e = ((s*8 + f)*64 + lane)*8 + j
//   maps to  o = 16*f + (lane&15),  ck = s*32 + 8*(lane>>4) + j,
//            k = ck>>6, c = ck&63,  value = W[(o*CIN + c)*KNB + k]
// ---------------------------------------------------------------------------
__global__ __launch_bounds__(256) void k_wconv(const float* __restrict__ W,
                                               unsigned short* __restrict__ Wb) {
    const int e = blockIdx.x * 256 + threadIdx.x;    // 0 .. 81919
    const int j = e & 7;
    const int l = (e >> 3) & 63;
    const int f = (e >> 9) & 7;
    const int s = e >> 12;                           // 0 .. 19
    const int o = 16 * f + (l & 15);
    const int ck = s * 32 + 8 * (l >> 4) + j;
    const int k = ck >> 6;
    const int c = ck & 63;
    Wb[e] = f2bf(W[(o * CIN + c) * KNB + k]);
}

// ---------------------------------------------------------------------------
// Main: per wave: 16 n-columns x all 128 o-rows, K=640 in 20 MFMA steps.
// B-fragment gathered directly from xT (one dwordx4/lane/step, no LDS).
// ---------------------------------------------------------------------------
__global__ __launch_bounds__(512) void k_main(const unsigned short* __restrict__ xT,
                                              const unsigned short* __restrict__ Wb,
                                              const float* __restrict__ bias,
                                              const int* __restrict__ idx,
                                              float* __restrict__ out) {
    const int t    = threadIdx.x;
    const int lane = t & 63;
    const int wv   = t >> 6;                 // 0..7
    const int b    = blockIdx.y;
    const int ln   = lane & 15;
    const int lg   = lane >> 4;              // 0..3
    const int n    = blockIdx.x * 128 + wv * 16 + ln;

    const char* xbase = (const char*)(xT + (size_t)b * NPTS * CIN);

    // Gather row byte-offsets for this n's 10 neighbors (row = 128 B).
    int rowoff[KNB];
    #pragma unroll
    for (int k = 0; k < KNB; ++k) {
        rowoff[k] = idx[n * KNB + k] * (CIN * 2);
    }

    f32x4 acc[8];
    #pragma unroll
    for (int f = 0; f < 8; ++f) acc[f] = (f32x4){0.f, 0.f, 0.f, 0.f};

    const bf16x8* wbase = (const bf16x8*)Wb;

    #pragma unroll
    for (int s = 0; s < NSTEP; ++s) {
        const int boff = rowoff[s >> 1] + (s & 1) * 64 + lg * 16;
        const bf16x8 bf = *(const bf16x8*)(xbase + boff);        // 16 B gather
        #pragma unroll
        for (int f = 0; f < 8; ++f) {
            const bf16x8 af = wbase[(s * 8 + f) * 64 + lane];    // coalesced, L1-hot
            acc[f] = __builtin_amdgcn_mfma_f32_16x16x32_bf16(af, bf, acc[f], 0, 0, 0);
        }
    }

    // Epilogue: D row = 4*lg + r (o), col = ln (n); add bias, store fp32.
    #pragma unroll
    for (int f = 0; f < 8; ++f) {
        #pragma unroll
        for (int r = 0; r < 4; ++r) {
            const int o = 16 * f + 4 * lg + r;
            out[(size_t)(b * COUT + o) * NPTS + n] = acc[f][r] + bias[o];
        }
    }
}

// ---------------------------------------------------------------------------
extern "C" void kernel_launch(void* const* d_in, const int* in_sizes, int n_in,
                              void* d_out, int out_size, void* d_ws, size_t ws_size,
                              hipStream_t stream) {
    const float* x    = (const float*)d_in[0];
    const int*   idx  = (const int*)d_in[1];
    const float* W    = (const float*)d_in[2];
    const float* bias = (const float*)d_in[3];
    float* out = (float*)d_out;

    // Workspace layout: xT bf16 (B*N*CIN*2 = 41.94 MB), then Wb bf16 (160 KB).
    unsigned short* xT = (unsigned short*)d_ws;
    unsigned short* Wb = (unsigned short*)((char*)d_ws + (size_t)BATCH * NPTS * CIN * 2);

    k_transpose<<<dim3(NPTS / 256, BATCH), 256, 0, stream>>>(x, xT);
    k_wconv<<<dim3((COUT * CK) / 256), 256, 0, stream>>>(W, Wb);
    k_main<<<dim3(NPTS / 128, BATCH), 512, 0, stream>>>(xT, Wb, bias, idx, out);
}

// Round 2
// 214.771 us; speedup vs baseline: 1.0318x; 1.0318x over previous
//
#include <hip/hip_runtime.h>
#include <hip/hip_bf16.h>
#include <stdint.h>

#define NPTS 81920
#define CIN  64
#define COUT 128
#define BATCH 4
#define KNB  10
#define CK   640      // CIN*KNB
#define NSTEP 20      // CK/32

typedef __attribute__((ext_vector_type(8))) short bf16x8;
typedef __attribute__((ext_vector_type(4))) float f32x4;

static __device__ __forceinline__ unsigned short f2bf(float f) {
    unsigned int u = __float_as_uint(f);
    u += 0x7fffu + ((u >> 16) & 1u);      // RNE, finite inputs
    return (unsigned short)(u >> 16);
}

// ---------------------------------------------------------------------------
// Kernel 1: x (B, CIN, N) f32  ->  xT (N, B, CIN) bf16
//   one gather row per point = 4 batches x 128 B = 512 B contiguous
// ---------------------------------------------------------------------------
__global__ __launch_bounds__(256) void k_transpose(const float* __restrict__ x,
                                                   unsigned short* __restrict__ xT) {
    const int m = blockIdx.x * 256 + threadIdx.x;
    const int b = blockIdx.y;
    const float* xb = x + (size_t)b * CIN * NPTS + m;

    unsigned int v[CIN / 2];
    #pragma unroll
    for (int i = 0; i < CIN / 2; ++i) {
        float f0 = xb[(size_t)(2 * i) * NPTS];       // coalesced across lanes
        float f1 = xb[(size_t)(2 * i + 1) * NPTS];
        v[i] = (unsigned int)f2bf(f0) | ((unsigned int)f2bf(f1) << 16);
    }
    uint4* dst = (uint4*)(xT + ((size_t)m * BATCH + b) * CIN);
    #pragma unroll
    for (int i = 0; i < 8; ++i) {
        uint4 w; w.x = v[4*i]; w.y = v[4*i+1]; w.z = v[4*i+2]; w.w = v[4*i+3];
        dst[i] = w;                                   // 128 B per lane
    }
}

// ---------------------------------------------------------------------------
// Kernel 2: W (COUT, CIN, KNB) f32 -> Wb bf16 in MFMA-fragment order:
//   element index e = ((s*8 + f)*64 + lane)*8 + j
//   maps to  o = 16*f + (lane&15),  ck = s*32 + 8*(lane>>4) + j,
//            k = ck>>6, c = ck&63,  value = W[(o*CIN + c)*KNB + k]
// ---------------------------------------------------------------------------
__global__ __launch_bounds__(256) void k_wconv(const float* __restrict__ W,
                                               unsigned short* __restrict__ Wb) {
    const int e = blockIdx.x * 256 + threadIdx.x;    // 0 .. 81919
    const int j = e & 7;
    const int l = (e >> 3) & 63;
    const int f = (e >> 9) & 7;
    const int s = e >> 12;                           // 0 .. 19
    const int o = 16 * f + (l & 15);
    const int ck = s * 32 + 8 * (l >> 4) + j;
    const int k = ck >> 6;
    const int c = ck & 63;
    Wb[e] = f2bf(W[(o * CIN + c) * KNB + k]);
}

// ---------------------------------------------------------------------------
// Main: per wave: 16 n-columns x 2 batches x all 128 o-rows.
// 20 K-steps of mfma_16x16x32; 2 gathers/step + next-step prefetch.
// ---------------------------------------------------------------------------
__global__ __launch_bounds__(512) void k_main(const unsigned short* __restrict__ xT,
                                              const unsigned short* __restrict__ Wb,
                                              const float* __restrict__ bias,
                                              const int* __restrict__ idx,
                                              float* __restrict__ out) {
    const int t    = threadIdx.x;
    const int lane = t & 63;
    const int wv   = t >> 6;                 // 0..7
    const int bz   = blockIdx.y;             // batch pair: {0,1} or {2,3}
    const int ln   = lane & 15;
    const int lg   = lane >> 4;              // 0..3
    const int n    = blockIdx.x * 128 + wv * 16 + ln;

    const char* xbase = (const char*)xT;
    const int bboff0 = (bz * 2 + 0) * (CIN * 2);
    const int bboff1 = (bz * 2 + 1) * (CIN * 2);

    // Gather row byte-offsets for this n's 10 neighbors (row = 512 B).
    int rowoff[KNB];
    #pragma unroll
    for (int k = 0; k < KNB; ++k) {
        rowoff[k] = idx[n * KNB + k] * (BATCH * CIN * 2);
    }

    f32x4 acc[8][2];
    #pragma unroll
    for (int f = 0; f < 8; ++f) {
        acc[f][0] = (f32x4){0.f, 0.f, 0.f, 0.f};
        acc[f][1] = (f32x4){0.f, 0.f, 0.f, 0.f};
    }

    const bf16x8* wbase = (const bf16x8*)Wb;

    bf16x8 c0, c1, p0, p1;
    {
        const int off = rowoff[0] + lg * 16;
        c0 = *(const bf16x8*)(xbase + off + bboff0);
        c1 = *(const bf16x8*)(xbase + off + bboff1);
    }

    #pragma unroll
    for (int s = 0; s < NSTEP; ++s) {
        if (s + 1 < NSTEP) {
            const int off = rowoff[(s + 1) >> 1] + ((s + 1) & 1) * 64 + lg * 16;
            p0 = *(const bf16x8*)(xbase + off + bboff0);
            p1 = *(const bf16x8*)(xbase + off + bboff1);
        }
        #pragma unroll
        for (int f = 0; f < 8; ++f) {
            const bf16x8 af = wbase[(s * 8 + f) * 64 + lane];    // coalesced
            acc[f][0] = __builtin_amdgcn_mfma_f32_16x16x32_bf16(af, c0, acc[f][0], 0, 0, 0);
            acc[f][1] = __builtin_amdgcn_mfma_f32_16x16x32_bf16(af, c1, acc[f][1], 0, 0, 0);
        }
        c0 = p0; c1 = p1;
    }

    // Epilogue: D row = 4*lg + r (o), col = ln (n); add bias, store fp32.
    #pragma unroll
    for (int f = 0; f < 8; ++f) {
        #pragma unroll
        for (int r = 0; r < 4; ++r) {
            const int o = 16 * f + 4 * lg + r;
            const float bv = bias[o];
            out[(size_t)((bz * 2 + 0) * COUT + o) * NPTS + n] = acc[f][0][r] + bv;
            out[(size_t)((bz * 2 + 1) * COUT + o) * NPTS + n] = acc[f][1][r] + bv;
        }
    }
}

// ---------------------------------------------------------------------------
extern "C" void kernel_launch(void* const* d_in, const int* in_sizes, int n_in,
                              void* d_out, int out_size, void* d_ws, size_t ws_size,
                              hipStream_t stream) {
    const float* x    = (const float*)d_in[0];
    const int*   idx  = (const int*)d_in[1];
    const float* W    = (const float*)d_in[2];
    const float* bias = (const float*)d_in[3];
    float* out = (float*)d_out;

    // Workspace layout: xT bf16 (N*B*CIN*2 = 41.94 MB), then Wb bf16 (160 KB).
    unsigned short* xT = (unsigned short*)d_ws;
    unsigned short* Wb = (unsigned short*)((char*)d_ws + (size_t)BATCH * NPTS * CIN * 2);

    k_transpose<<<dim3(NPTS / 256, BATCH), 256, 0, stream>>>(x, xT);
    k_wconv<<<dim3((COUT * CK) / 256), 256, 0, stream>>>(W, Wb);
    k_main<<<dim3(NPTS / 128, 2), 512, 0, stream>>>(xT, Wb, bias, idx, out);
}

// Round 3
// 133.065 us; speedup vs baseline: 1.6653x; 1.6140x over previous
//
#include <hip/hip_runtime.h>
#include <hip/hip_bf16.h>
#include <stdint.h>

#define NPTS 81920
#define CIN  64
#define COUT 128
#define BATCH 4
#define KNB  10
#define CK   640      // CIN*KNB
#define NT   64       // n-tile per block

typedef __attribute__((ext_vector_type(8))) short bf16x8;
typedef __attribute__((ext_vector_type(4))) float f32x4;

static __device__ __forceinline__ unsigned short f2bf(float f) {
    unsigned int u = __float_as_uint(f);
    u += 0x7fffu + ((u >> 16) & 1u);      // RNE, finite inputs
    return (unsigned short)(u >> 16);
}

static __device__ __forceinline__ void gload16(const void* g, void* l) {
    __builtin_amdgcn_global_load_lds(
        (const __attribute__((address_space(1))) unsigned int*)g,
        (__attribute__((address_space(3))) unsigned int*)l, 16, 0, 0);
}

// ---------------------------------------------------------------------------
// Kernel 1: x (B, CIN, N) f32  ->  xT (N, B, CIN) bf16
//   one gather row per point = 4 batches x 128 B = 512 B contiguous
// ---------------------------------------------------------------------------
__global__ __launch_bounds__(256) void k_transpose(const float* __restrict__ x,
                                                   unsigned short* __restrict__ xT) {
    const int m = blockIdx.x * 256 + threadIdx.x;
    const int b = blockIdx.y;
    const float* xb = x + (size_t)b * CIN * NPTS + m;

    unsigned int v[CIN / 2];
    #pragma unroll
    for (int i = 0; i < CIN / 2; ++i) {
        float f0 = xb[(size_t)(2 * i) * NPTS];       // coalesced across lanes
        float f1 = xb[(size_t)(2 * i + 1) * NPTS];
        v[i] = (unsigned int)f2bf(f0) | ((unsigned int)f2bf(f1) << 16);
    }
    uint4* dst = (uint4*)(xT + ((size_t)m * BATCH + b) * CIN);
    #pragma unroll
    for (int i = 0; i < 8; ++i) {
        uint4 w; w.x = v[4*i]; w.y = v[4*i+1]; w.z = v[4*i+2]; w.w = v[4*i+3];
        dst[i] = w;                                   // 128 B per lane
    }
}

// ---------------------------------------------------------------------------
// Kernel 2: W (COUT, CIN, KNB) f32 -> Wb bf16 in MFMA-fragment order:
//   element index e = ((s*8 + f)*64 + lane)*8 + j
//   maps to  o = 16*f + (lane&15),  ck = s*32 + 8*(lane>>4) + j,
//            k = ck>>6, c = ck&63,  value = W[(o*CIN + c)*KNB + k]
// ---------------------------------------------------------------------------
__global__ __launch_bounds__(256) void k_wconv(const float* __restrict__ W,
                                               unsigned short* __restrict__ Wb) {
    const int e = blockIdx.x * 256 + threadIdx.x;    // 0 .. 81919
    const int j = e & 7;
    const int l = (e >> 3) & 63;
    const int f = (e >> 9) & 7;
    const int s = e >> 12;                           // 0 .. 19
    const int o = 16 * f + (l & 15);
    const int ck = s * 32 + 8 * (l >> 4) + j;
    const int k = ck >> 6;
    const int c = ck & 63;
    Wb[e] = f2bf(W[(o * CIN + c) * KNB + k]);
}

// ---------------------------------------------------------------------------
// Main: block = 8 waves, n-tile 64, batch-pair bz (grid.y), wave = o-frag wv.
// Gathered rows staged in LDS (double-buffered, global_load_lds with
// pre-swizzled source); each wave reads only its own 20 KB of Wb.
// ---------------------------------------------------------------------------
__global__ __launch_bounds__(512, 4) void k_main(const unsigned short* __restrict__ xT,
                                                 const unsigned short* __restrict__ Wb,
                                                 const float* __restrict__ bias,
                                                 const int* __restrict__ idx,
                                                 float* __restrict__ out) {
    // smem[buf][row][256 B]: row = n-local, 256 B = 2 batches x 64 bf16 (one k)
    __shared__ char smem[2][NT][256];

    const int t    = threadIdx.x;
    const int lane = t & 63;
    const int wv   = t >> 6;                 // o-frag 0..7
    const int ln   = lane & 15;
    const int lg   = lane >> 4;              // 0..3
    const int bz   = blockIdx.y;             // batch pair
    const int nb   = blockIdx.x * NT;

    const char* xbase = (const char*)xT + bz * 256;
    const bf16x8* wbase = (const bf16x8*)Wb;

    f32x4 acc[4][2];
    #pragma unroll
    for (int j = 0; j < 4; ++j) {
        acc[j][0] = (f32x4){0.f, 0.f, 0.f, 0.f};
        acc[j][1] = (f32x4){0.f, 0.f, 0.f, 0.f};
    }

    // Stage iteration k: 64 rows x 256 B into smem[k&1]. Wave stages 8 rows
    // (2 insts, 4 rows each). Global source pre-swizzled so linear LDS dest
    // + XOR-swizzled reads are conflict-free.
    #define STAGE(k)                                                            \
        {                                                                       \
            _Pragma("unroll")                                                   \
            for (int i = 0; i < 2; ++i) {                                       \
                const int row   = (wv << 3) + (i << 2) + (lane >> 4);           \
                const int nglob = nb + row;                                     \
                const int r     = idx[nglob * KNB + (k)];                       \
                const char* src = xbase + (size_t)r * 512 +                     \
                                  (((lane & 15) * 16) ^ ((row & 7) << 4));      \
                gload16(src, &smem[(k) & 1][(wv << 3) + (i << 2)][0]);          \
            }                                                                   \
        }

    STAGE(0);
    bf16x8 a0 = wbase[(0 * 8 + wv) * 64 + lane];
    bf16x8 a1 = wbase[(1 * 8 + wv) * 64 + lane];
    __syncthreads();                          // drains vmcnt(0): stage(0) landed

    #pragma unroll
    for (int k = 0; k < KNB; ++k) {
        if (k + 1 < KNB) STAGE(k + 1);        // async into other buffer
        bf16x8 a0n = a0, a1n = a1;
        if (k + 1 < KNB) {
            a0n = wbase[((2 * k + 2) * 8 + wv) * 64 + lane];
            a1n = wbase[((2 * k + 3) * 8 + wv) * 64 + lane];
        }
        #pragma unroll
        for (int h = 0; h < 2; ++h) {
            const bf16x8 a = h ? a1 : a0;
            #pragma unroll
            for (int j = 0; j < 4; ++j) {
                const int row = j * 16 + ln;
                const int sw  = (row & 7) << 4;
                #pragma unroll
                for (int bb = 0; bb < 2; ++bb) {
                    const int byte = bb * 128 + ((h * 64 + lg * 16) ^ sw);
                    const bf16x8 bf = *(const bf16x8*)&smem[k & 1][row][byte];
                    acc[j][bb] = __builtin_amdgcn_mfma_f32_16x16x32_bf16(
                        a, bf, acc[j][bb], 0, 0, 0);
                }
            }
        }
        __syncthreads();                      // drains stage(k+1) + WAR fence
        a0 = a0n; a1 = a1n;
    }
    #undef STAGE

    // Epilogue: o = 16*wv + 4*lg + r; n = nb + j*16 + ln; b = bz*2 + bb.
    #pragma unroll
    for (int j = 0; j < 4; ++j) {
        const int n = nb + j * 16 + ln;
        #pragma unroll
        for (int bb = 0; bb < 2; ++bb) {
            const int b = bz * 2 + bb;
            #pragma unroll
            for (int r = 0; r < 4; ++r) {
                const int o = 16 * wv + 4 * lg + r;
                out[(size_t)(b * COUT + o) * NPTS + n] = acc[j][bb][r] + bias[o];
            }
        }
    }
}

// ---------------------------------------------------------------------------
extern "C" void kernel_launch(void* const* d_in, const int* in_sizes, int n_in,
                              void* d_out, int out_size, void* d_ws, size_t ws_size,
                              hipStream_t stream) {
    const float* x    = (const float*)d_in[0];
    const int*   idx  = (const int*)d_in[1];
    const float* W    = (const float*)d_in[2];
    const float* bias = (const float*)d_in[3];
    float* out = (float*)d_out;

    // Workspace layout: xT bf16 (N*B*CIN*2 = 41.94 MB), then Wb bf16 (160 KB).
    unsigned short* xT = (unsigned short*)d_ws;
    unsigned short* Wb = (unsigned short*)((char*)d_ws + (size_t)BATCH * NPTS * CIN * 2);

    k_transpose<<<dim3(NPTS / 256, BATCH), 256, 0, stream>>>(x, xT);
    k_wconv<<<dim3((COUT * CK) / 256), 256, 0, stream>>>(W, Wb);
    k_main<<<dim3(NPTS / NT, 2), 512, 0, stream>>>(xT, Wb, bias, idx, out);
}